// Round 5
// baseline (1112.632 us; speedup 1.0000x reference)
//
#include <hip/hip_runtime.h>
#include <hip/hip_bf16.h>
#include <math.h>

// ---------------------------------------------------------------------------
// LinearCrossEntropy via MX-fp8 MFMA (16x16x128 f8f6f4, uniform HW scales).
// R5:
//   * LDS restructured as TWO 64B-row planes per operand (plane h holds
//     k in [64h,64h+64)), with R2's measured-zero swizzle c^((row>>1)&3).
//     granule(lane) = (lm&1)*4 + slot, slot in 0..3 -> 8-lane phases cover
//     all 8 granules exactly once (SQ_LDS_BANK_CONFLICT was exactly 0 for
//     this address function in R2; R3/R4's 128B-row variant measured 5.15e7).
//   * 2 dispatches total: cast (also zero-inits accumulators) and gemm
//     (per-mt last-block computes nll, global last-block writes the mean).
//     Cross-XCD visibility: row_sum via atomic RMW, tgt via agent-scope
//     atomic stores, counters via acq_rel agent atomics, reads via agent
//     atomic loads after the acquire.
// ---------------------------------------------------------------------------

#define BM 128
#define BN 128
#define BKB 128  // K bytes (fp8) per tile iteration

typedef int   i32x8 __attribute__((ext_vector_type(8)));
typedef float f32x4 __attribute__((ext_vector_type(4)));

__device__ __forceinline__ void load_lds16(const void* g, void* l) {
    __builtin_amdgcn_global_load_lds(
        (const __attribute__((address_space(1))) void*)g,
        (__attribute__((address_space(3))) void*)l, 16, 0, 0);
}

// ---- fp8 e4m3fn conversion -------------------------------------------------
__device__ __forceinline__ unsigned char f2e4m3_sw(float x) {
    unsigned u = __float_as_uint(x);
    unsigned s = (u >> 24) & 0x80;
    float ax = __uint_as_float(u & 0x7fffffff);
    if (ax != ax) return (unsigned char)(s | 0x7f);
    if (ax >= 448.f) return (unsigned char)(s | 0x7e);
    if (ax < 0.0009765625f) return (unsigned char)s;
    if (ax < 0.015625f) {
        int n = (int)rintf(ax * 512.f);
        return (unsigned char)(s | n);
    }
    int e = (int)((u >> 23) & 0xff) - 127;
    unsigned m = u & 0x7fffff;
    unsigned keep = m >> 20, rest = m & 0xfffff;
    if (rest > 0x80000u || (rest == 0x80000u && (keep & 1))) keep++;
    if (keep == 8) { keep = 0; e++; if (e > 8) return (unsigned char)(s | 0x7e); }
    return (unsigned char)(s | ((e + 7) << 3) | keep);
}

__device__ __forceinline__ unsigned int pk4_fp8(float a, float b, float c, float d) {
#if __has_builtin(__builtin_amdgcn_cvt_pk_fp8_f32)
    int v = __builtin_amdgcn_cvt_pk_fp8_f32(a, b, 0, false);
    v = __builtin_amdgcn_cvt_pk_fp8_f32(c, d, v, true);
    return (unsigned int)v;
#else
    return (unsigned int)f2e4m3_sw(a) | ((unsigned int)f2e4m3_sw(b) << 8) |
           ((unsigned int)f2e4m3_sw(c) << 16) | ((unsigned int)f2e4m3_sw(d) << 24);
#endif
}

// Combined cast + accumulator zero-init.
// [0,ne): e (scale 1) -> e_f8 ; [ne, ne+ncd): c (scale 16, zero past ncs).
// First zwords threads also zero the accumulator region (row_sum/gacc/counters).
__global__ void cast_all_fp8(const float* __restrict__ e,
                             const float* __restrict__ c,
                             unsigned char* __restrict__ e_f8,
                             unsigned char* __restrict__ c_f8,
                             unsigned int* __restrict__ zbase, int zwords,
                             long ne, long ncs, long ncd) {
    long tid = (long)blockIdx.x * blockDim.x + threadIdx.x;
    if (tid < zwords) zbase[tid] = 0u;
    long i8 = tid * 8;
    if (i8 >= ne + ncd) return;
    const float* src;
    unsigned char* dst;
    float scale;
    bool zero = false;
    if (i8 < ne) {
        src = e + i8; dst = e_f8 + i8; scale = 1.0f;
    } else {
        long j8 = i8 - ne;
        dst = c_f8 + j8; scale = 16.0f;
        src = c + j8;
        zero = (j8 + 7 >= ncs);
    }
    uint2 o;
    if (!zero) {
        float4 v0 = *(const float4*)(src);
        float4 v1 = *(const float4*)(src + 4);
        o.x = pk4_fp8(v0.x * scale, v0.y * scale, v0.z * scale, v0.w * scale);
        o.y = pk4_fp8(v1.x * scale, v1.y * scale, v1.z * scale, v1.w * scale);
    } else {
        o.x = o.y = 0u;
    }
    *(uint2*)dst = o;
}

// ---- fused GEMM + sum-exp + target logit + full CE reduction ---------------
// E: [N][D] fp8, C: [Vpad][D] fp8 (zero-pad rows).
// row_sum[N] (atomic), gacc[2] (sum,count), done[1], mt_cnt[mtiles]: pre-zeroed.
__global__ __launch_bounds__(256)
void gemm_lse_fused(const unsigned char* __restrict__ E,
                    const unsigned char* __restrict__ C,
                    const float* __restrict__ bias,
                    const int* __restrict__ targets,
                    float* __restrict__ row_sum,
                    float* __restrict__ tgt,
                    float* __restrict__ gacc,
                    int* __restrict__ done,
                    int* __restrict__ mt_cnt,
                    float* __restrict__ out,
                    int N, int D, int V, int vtiles, int mtiles) {
    // Each operand: 2 planes x (64 rows-stride... rows 0..127) x 64 B rows.
    // LDS offset of (plane h, row r, slot s) = h*8192 + r*64 + s*16,
    // slot s holds original 16B chunk c = s ^ ((r>>1)&3).
    __shared__ unsigned char As[2 * BM * 64];  // 16 KB
    __shared__ unsigned char Bs[2 * BN * 64];  // 16 KB
    __shared__ float bias_s[BN];
    __shared__ int tgt_s[BM];
    __shared__ float red_s[2][BM];
    __shared__ float fin[8];
    __shared__ int is_last;

    const int t = threadIdx.x;
    const int w = t >> 6;
    const int l = t & 63;
    const int quad = l >> 4;
    const int lm = l & 15;
    const int wr0 = (w >> 1) * 64;
    const int wc0 = (w & 1) * 64;

    const int mt = blockIdx.x;
    const int vt = blockIdx.y;

    if (t < BN) {
        int col = vt * BN + t;
        bias_s[t] = (col < V) ? bias[col] : -INFINITY;
    }
    if (t >= BN && t < BN + BM)
        tgt_s[t - BN] = targets[mt * BM + (t - BN)];

    // staging: round ro, thread t -> plane h=ro>>1, row=(ro&1)*64+(t>>2),
    // stored slot t&3 holding chunk (t&3)^((t>>3)&3)  [(row>>1)&3=(t>>3)&3].
    const int schunk = (t & 3) ^ ((t >> 3) & 3);
    const unsigned char* ga = E + (long)(mt * BM + (t >> 2)) * D + schunk * 16;
    const unsigned char* gb = C + (long)(vt * BN + (t >> 2)) * D + schunk * 16;
    char* lA = (char*)As + w * 1024;  // wave-uniform LDS base (+ lane*16 by HW)
    char* lB = (char*)Bs + w * 1024;
    const long roff0 = 0, roff1 = 64L * D, roff2 = 64, roff3 = 64L * D + 64;

    f32x4 acc[4][4] = {};
    const int sA = 127;  // e8m0 2^0
    const int sB = 123;  // e8m0 2^-4 (undoes *16 in cast)

    for (int k0 = 0; k0 < D; k0 += BKB) {
        load_lds16(ga + k0 + roff0, lA);
        load_lds16(ga + k0 + roff1, lA + 4096);
        load_lds16(ga + k0 + roff2, lA + 8192);
        load_lds16(ga + k0 + roff3, lA + 12288);
        load_lds16(gb + k0 + roff0, lB);
        load_lds16(gb + k0 + roff1, lB + 4096);
        load_lds16(gb + k0 + roff2, lB + 8192);
        load_lds16(gb + k0 + roff3, lB + 12288);
        __syncthreads();

        // fragment: k-range [32q,32q+32) = plane q>>1, chunks {2(q&1), +1};
        // slot0 = (2(q&1)) ^ ((lm>>1)&3), slot1 = slot0^1.
        const int h_off = (quad >> 1) * 8192;
        const int s0 = (((quad & 1) << 1) ^ ((lm >> 1) & 3)) << 4;
        const int s1 = s0 ^ 16;
        i32x8 a_frag[4], b_frag[4];
#pragma unroll
        for (int ti = 0; ti < 4; ti++) {
            const unsigned char* pr = As + h_off + (wr0 + ti * 16 + lm) * 64;
            int4 lo = *(const int4*)(pr + s0);
            int4 hi = *(const int4*)(pr + s1);
            a_frag[ti] = (i32x8){lo.x, lo.y, lo.z, lo.w, hi.x, hi.y, hi.z, hi.w};
        }
#pragma unroll
        for (int tj = 0; tj < 4; tj++) {
            const unsigned char* pr = Bs + h_off + (wc0 + tj * 16 + lm) * 64;
            int4 lo = *(const int4*)(pr + s0);
            int4 hi = *(const int4*)(pr + s1);
            b_frag[tj] = (i32x8){lo.x, lo.y, lo.z, lo.w, hi.x, hi.y, hi.z, hi.w};
        }
#pragma unroll
        for (int ti = 0; ti < 4; ti++)
#pragma unroll
            for (int tj = 0; tj < 4; tj++)
                acc[ti][tj] = __builtin_amdgcn_mfma_scale_f32_16x16x128_f8f6f4(
                    a_frag[ti], b_frag[tj], acc[ti][tj], 0, 0, 0, sA, 0, sB);
        __syncthreads();
    }

    // ---- epilogue: sum-exp over this tile's 128 cols + target extraction ---
    // acc[ti][tj][r] = (row = wr0+ti*16+quad*4+r, col = wc0+tj*16+lm)
    float bvals[4];
#pragma unroll
    for (int tj = 0; tj < 4; tj++) bvals[tj] = bias_s[wc0 + tj * 16 + lm];

#pragma unroll
    for (int ti = 0; ti < 4; ti++) {
#pragma unroll
        for (int r = 0; r < 4; r++) {
            const int row_local = wr0 + ti * 16 + quad * 4 + r;
            const int tl = tgt_s[row_local] - vt * BN - wc0;  // local to wave cols
            float srow_ = 0.f;
#pragma unroll
            for (int tj = 0; tj < 4; tj++) {
                float v = acc[ti][tj][r] + bvals[tj];   // pad col: exp(-inf)=0
                srow_ += __expf(v);
                if (tj * 16 + lm == tl)                 // target-logit extraction
                    __hip_atomic_store(&tgt[mt * BM + row_local], v,
                                       __ATOMIC_RELAXED, __HIP_MEMORY_SCOPE_AGENT);
            }
#pragma unroll
            for (int off = 1; off < 16; off <<= 1)
                srow_ += __shfl_xor(srow_, off, 64);
            if (lm == 0)
                red_s[w & 1][row_local] = srow_;
        }
    }
    __syncthreads();
    if (t < BM)
        atomicAdd(&row_sum[mt * BM + t], red_s[0][t] + red_s[1][t]);
    __syncthreads();  // drains vmcnt: atomics + tgt stores complete device-wide

    // ---- per-mt completion: last block of this mt computes its 128 nll -----
    if (t == 0) {
        int d = __hip_atomic_fetch_add(&mt_cnt[mt], 1,
                                       __ATOMIC_ACQ_REL, __HIP_MEMORY_SCOPE_AGENT);
        is_last = (d == vtiles - 1);
    }
    __syncthreads();
    if (!is_last) return;

    float nllv = 0.f, cntv = 0.f;
    if (t < BM) {
        int r = mt * BM + t;
        int tg = targets[r];
        if (tg != -100) {
            float s = __hip_atomic_load(&row_sum[r], __ATOMIC_RELAXED,
                                        __HIP_MEMORY_SCOPE_AGENT);
            float tv = __hip_atomic_load(&tgt[r], __ATOMIC_RELAXED,
                                         __HIP_MEMORY_SCOPE_AGENT);
            nllv = logf(s) - tv;
            cntv = 1.f;
        }
    }
#pragma unroll
    for (int off = 32; off; off >>= 1) {
        nllv += __shfl_xor(nllv, off, 64);
        cntv += __shfl_xor(cntv, off, 64);
    }
    if (l == 0) { fin[w] = nllv; fin[4 + w] = cntv; }
    __syncthreads();
    if (t == 0) {
        atomicAdd(gacc,     fin[0] + fin[1] + fin[2] + fin[3]);
        atomicAdd(gacc + 1, fin[4] + fin[5] + fin[6] + fin[7]);
        int d = __hip_atomic_fetch_add(done, 1,
                                       __ATOMIC_ACQ_REL, __HIP_MEMORY_SCOPE_AGENT);
        if (d == mtiles - 1) {
            float S = __hip_atomic_load(gacc, __ATOMIC_RELAXED,
                                        __HIP_MEMORY_SCOPE_AGENT);
            float Cn = __hip_atomic_load(gacc + 1, __ATOMIC_RELAXED,
                                         __HIP_MEMORY_SCOPE_AGENT);
            out[0] = S / fmaxf(Cn, 1.f);
        }
    }
}

extern "C" void kernel_launch(void* const* d_in, const int* in_sizes, int n_in,
                              void* d_out, int out_size, void* d_ws, size_t ws_size,
                              hipStream_t stream) {
    const float* e       = (const float*)d_in[0];
    const float* c       = (const float*)d_in[1];
    const int*   targets = (const int*)d_in[2];
    const float* bias    = (const float*)d_in[3];
    float* out = (float*)d_out;

    const int N = in_sizes[2];            // 8192
    const int V = in_sizes[3];            // 50257
    const int D = in_sizes[0] / N;        // 1024
    const int mtiles = N / BM;            // 64
    const int vtiles = (V + BN - 1) / BN; // 393
    const long Vpad = (long)vtiles * BN;  // 50304

    char* ws = (char*)d_ws;
    size_t off = 0;
    auto alloc = [&](size_t bytes) {
        void* p = ws + off;
        off += (bytes + 255) & ~(size_t)255;
        return p;
    };
    unsigned char* e_f8 = (unsigned char*)alloc((size_t)N * D);
    unsigned char* c_f8 = (unsigned char*)alloc((size_t)Vpad * D);
    // zero-init region: row_sum[N] | gacc[2] | done[1] | mt_cnt[mtiles]
    const int zwords = N + 2 + 1 + mtiles;
    float* row_sum = (float*)alloc((size_t)zwords * 4);
    float* gacc    = row_sum + N;
    int*   done    = (int*)(row_sum + N + 2);
    int*   mt_cnt  = (int*)(row_sum + N + 3);
    float* tgt     = (float*)alloc((size_t)N * 4);

    const long ne  = (long)N * D;
    const long ncs = (long)V * D;
    const long ncd = Vpad * D;
    const long tot8 = (ne + ncd) / 8;
    cast_all_fp8<<<(int)((tot8 + 255) / 256), 256, 0, stream>>>(
        e, c, e_f8, c_f8, (unsigned int*)row_sum, zwords, ne, ncs, ncd);

    dim3 grid(mtiles, vtiles);
    gemm_lse_fused<<<grid, 256, 0, stream>>>(
        e_f8, c_f8, bias, targets, row_sum, tgt, gacc, done, mt_cnt, out,
        N, D, V, vtiles, mtiles);
}

// Round 6
// 824.558 us; speedup vs baseline: 1.3494x; 1.3494x over previous
//
#include <hip/hip_runtime.h>
#include <hip/hip_bf16.h>
#include <math.h>

// ---------------------------------------------------------------------------
// LinearCrossEntropy via MX-fp8 MFMA (16x16x128 f8f6f4, uniform HW scales).
// R6:
//   * GEMM reverted to R4's proven 605 µs version (R5's per-block acq_rel
//     completion caused a uniform ~1.5x stall; SQ_LDS_BANK_CONFLICT proved
//     layout-invariant at exactly 5.151e7 across 3 layouts -> parked).
//   * Cast rewritten: 16 elems/thread, 64B reads + 16B uint4 stores,
//     block-uniform region split (no per-thread divergence), fused zero-init.
//   * lse_finish + final_scalar merged into one single-block kernel.
// Dispatches: cast_all_fp8, gemm_lse_partial, finish.
// ---------------------------------------------------------------------------

#define BM 128
#define BN 128
#define BKB 128  // K bytes (fp8) per tile iteration

typedef int   i32x8 __attribute__((ext_vector_type(8)));
typedef float f32x4 __attribute__((ext_vector_type(4)));

__device__ __forceinline__ void load_lds16(const void* g, void* l) {
    __builtin_amdgcn_global_load_lds(
        (const __attribute__((address_space(1))) void*)g,
        (__attribute__((address_space(3))) void*)l, 16, 0, 0);
}

// ---- fp8 e4m3fn conversion -------------------------------------------------
__device__ __forceinline__ unsigned char f2e4m3_sw(float x) {
    unsigned u = __float_as_uint(x);
    unsigned s = (u >> 24) & 0x80;
    float ax = __uint_as_float(u & 0x7fffffff);
    if (ax != ax) return (unsigned char)(s | 0x7f);
    if (ax >= 448.f) return (unsigned char)(s | 0x7e);
    if (ax < 0.0009765625f) return (unsigned char)s;
    if (ax < 0.015625f) {
        int n = (int)rintf(ax * 512.f);
        return (unsigned char)(s | n);
    }
    int e = (int)((u >> 23) & 0xff) - 127;
    unsigned m = u & 0x7fffff;
    unsigned keep = m >> 20, rest = m & 0xfffff;
    if (rest > 0x80000u || (rest == 0x80000u && (keep & 1))) keep++;
    if (keep == 8) { keep = 0; e++; if (e > 8) return (unsigned char)(s | 0x7e); }
    return (unsigned char)(s | ((e + 7) << 3) | keep);
}

__device__ __forceinline__ unsigned int pk4_fp8(float a, float b, float c, float d) {
#if __has_builtin(__builtin_amdgcn_cvt_pk_fp8_f32)
    int v = __builtin_amdgcn_cvt_pk_fp8_f32(a, b, 0, false);
    v = __builtin_amdgcn_cvt_pk_fp8_f32(c, d, v, true);
    return (unsigned int)v;
#else
    return (unsigned int)f2e4m3_sw(a) | ((unsigned int)f2e4m3_sw(b) << 8) |
           ((unsigned int)f2e4m3_sw(c) << 16) | ((unsigned int)f2e4m3_sw(d) << 24);
#endif
}

// Region-split cast, 16 elems/thread, 16B stores.
// blocks [0, eblocks): e (scale 1) -> e_f8          (ne = eblocks*4096 exactly)
// blocks [eblocks, ..): c (scale 16) -> c_f8, zero past ncs (ncs % 16 == 0)
// First zwords threads also zero the accumulator region.
__global__ void cast_all_fp8(const float* __restrict__ e,
                             const float* __restrict__ c,
                             unsigned char* __restrict__ e_f8,
                             unsigned char* __restrict__ c_f8,
                             unsigned int* __restrict__ zbase, int zwords,
                             long ncs, int eblocks) {
    long tid = (long)blockIdx.x * 256 + threadIdx.x;
    if (tid < zwords) zbase[tid] = 0u;

    const float* src;
    unsigned char* dst;
    float scale;
    if (blockIdx.x < eblocks) {
        long idx = tid * 16;
        src = e + idx; dst = e_f8 + idx; scale = 1.0f;
    } else {
        long j = ((long)(blockIdx.x - eblocks) * 256 + threadIdx.x) * 16;
        dst = c_f8 + j; scale = 16.0f;
        if (j >= ncs) {                       // zero padding region
            *(uint4*)dst = (uint4){0u, 0u, 0u, 0u};
            return;
        }
        src = c + j;
    }
    float4 v0 = *(const float4*)(src);
    float4 v1 = *(const float4*)(src + 4);
    float4 v2 = *(const float4*)(src + 8);
    float4 v3 = *(const float4*)(src + 12);
    uint4 o;
    o.x = pk4_fp8(v0.x * scale, v0.y * scale, v0.z * scale, v0.w * scale);
    o.y = pk4_fp8(v1.x * scale, v1.y * scale, v1.z * scale, v1.w * scale);
    o.z = pk4_fp8(v2.x * scale, v2.y * scale, v2.z * scale, v2.w * scale);
    o.w = pk4_fp8(v3.x * scale, v3.y * scale, v3.z * scale, v3.w * scale);
    *(uint4*)dst = o;
}

// ---- GEMM 128x128x(K=128/iter), fused sum-exp + target-logit epilogue ------
// (verbatim R4 structure: measured 605 us / 1394 TF)
__global__ __launch_bounds__(256)
void gemm_lse_partial(const unsigned char* __restrict__ E,
                      const unsigned char* __restrict__ C,
                      const float* __restrict__ bias,
                      const int* __restrict__ targets,
                      float* __restrict__ row_sum,
                      float* __restrict__ tgt,
                      int N, int D, int V) {
    __shared__ unsigned char As[BM * BKB];  // 16 KB; row r chunk c at (c^(r&7))*16
    __shared__ unsigned char Bs[BN * BKB];  // 16 KB
    __shared__ float bias_s[BN];
    __shared__ int tgt_s[BM];
    __shared__ float red_s[2][BM];

    const int t = threadIdx.x;
    const int w = t >> 6;
    const int l = t & 63;
    const int quad = l >> 4;
    const int lm = l & 15;
    const int wr0 = (w >> 1) * 64;
    const int wc0 = (w & 1) * 64;

    const int mt = blockIdx.x;
    const int vt = blockIdx.y;

    if (t < BN) {
        int col = vt * BN + t;
        bias_s[t] = (col < V) ? bias[col] : -INFINITY;
    }
    if (t >= BN && t < BN + BM)
        tgt_s[t - BN] = targets[mt * BM + (t - BN)];

    // staging: round ro, thread t -> row ro*32+(t>>3), stored chunk t&7,
    // holding original chunk (t&7)^(row&7).
    const int srow = t >> 3;
    const int schunk = (t & 7) ^ (srow & 7);
    const unsigned char* ga = E + (long)(mt * BM + srow) * D + schunk * 16;
    const unsigned char* gb = C + (long)(vt * BN + srow) * D + schunk * 16;
    char* lA = (char*)As + w * 1024;  // wave-uniform LDS base (+ lane*16 by HW)
    char* lB = (char*)Bs + w * 1024;
    const long rnd = 32L * D;

    f32x4 acc[4][4] = {};
    const int sA = 127;  // e8m0 2^0
    const int sB = 123;  // e8m0 2^-4 (undoes *16 in cast)

    for (int k0 = 0; k0 < D; k0 += BKB) {
#pragma unroll
        for (int ro = 0; ro < 4; ro++) {
            load_lds16(ga + k0 + ro * rnd, lA + ro * 4096);
            load_lds16(gb + k0 + ro * rnd, lB + ro * 4096);
        }
        __syncthreads();

        const int c0 = ((quad << 1) ^ (lm & 7)) << 4;
        const int c1 = c0 ^ 16;
        i32x8 a_frag[4], b_frag[4];
#pragma unroll
        for (int ti = 0; ti < 4; ti++) {
            const unsigned char* pr = As + (wr0 + ti * 16 + lm) * 128;
            int4 lo = *(const int4*)(pr + c0);
            int4 hi = *(const int4*)(pr + c1);
            a_frag[ti] = (i32x8){lo.x, lo.y, lo.z, lo.w, hi.x, hi.y, hi.z, hi.w};
        }
#pragma unroll
        for (int tj = 0; tj < 4; tj++) {
            const unsigned char* pr = Bs + (wc0 + tj * 16 + lm) * 128;
            int4 lo = *(const int4*)(pr + c0);
            int4 hi = *(const int4*)(pr + c1);
            b_frag[tj] = (i32x8){lo.x, lo.y, lo.z, lo.w, hi.x, hi.y, hi.z, hi.w};
        }
#pragma unroll
        for (int ti = 0; ti < 4; ti++)
#pragma unroll
            for (int tj = 0; tj < 4; tj++)
                acc[ti][tj] = __builtin_amdgcn_mfma_scale_f32_16x16x128_f8f6f4(
                    a_frag[ti], b_frag[tj], acc[ti][tj], 0, 0, 0, sA, 0, sB);
        __syncthreads();
    }

    // ---- epilogue ----
    float bvals[4];
#pragma unroll
    for (int tj = 0; tj < 4; tj++) bvals[tj] = bias_s[wc0 + tj * 16 + lm];

#pragma unroll
    for (int ti = 0; ti < 4; ti++) {
#pragma unroll
        for (int r = 0; r < 4; r++) {
            const int row_local = wr0 + ti * 16 + quad * 4 + r;
            const int tl = tgt_s[row_local] - vt * BN;
            float srow_ = 0.f;
#pragma unroll
            for (int tj = 0; tj < 4; tj++) {
                float v = acc[ti][tj][r] + bvals[tj];   // pad col: exp(-inf)=0
                srow_ += __expf(v);
                if (wc0 + tj * 16 + lm == tl)           // target-logit extraction
                    tgt[mt * BM + row_local] = v;
            }
#pragma unroll
            for (int off = 1; off < 16; off <<= 1)
                srow_ += __shfl_xor(srow_, off, 64);
            if (lm == 0)
                red_s[w & 1][row_local] = srow_;
        }
    }
    __syncthreads();
    if (t < BM)
        atomicAdd(&row_sum[(long)mt * BM + t], red_s[0][t] + red_s[1][t]);
}

// Single-block finisher: nll over all rows + mean.
__global__ void finish(const float* __restrict__ row_sum,
                       const float* __restrict__ tgt,
                       const int* __restrict__ targets,
                       float* __restrict__ out, int N) {
    __shared__ float sred[32];
    float nll = 0.f, cnt = 0.f;
    for (int r = threadIdx.x; r < N; r += 1024) {
        int tg = targets[r];
        if (tg != -100) { nll += logf(row_sum[r]) - tgt[r]; cnt += 1.f; }
    }
#pragma unroll
    for (int off = 32; off; off >>= 1) {
        nll += __shfl_xor(nll, off, 64);
        cnt += __shfl_xor(cnt, off, 64);
    }
    int w = threadIdx.x >> 6, l = threadIdx.x & 63;
    if (l == 0) { sred[w] = nll; sred[16 + w] = cnt; }
    __syncthreads();
    if (threadIdx.x == 0) {
        float S = 0.f, C = 0.f;
        for (int i = 0; i < 16; i++) { S += sred[i]; C += sred[16 + i]; }
        out[0] = S / fmaxf(C, 1.f);
    }
}

extern "C" void kernel_launch(void* const* d_in, const int* in_sizes, int n_in,
                              void* d_out, int out_size, void* d_ws, size_t ws_size,
                              hipStream_t stream) {
    const float* e       = (const float*)d_in[0];
    const float* c       = (const float*)d_in[1];
    const int*   targets = (const int*)d_in[2];
    const float* bias    = (const float*)d_in[3];
    float* out = (float*)d_out;

    const int N = in_sizes[2];            // 8192
    const int V = in_sizes[3];            // 50257
    const int D = in_sizes[0] / N;        // 1024
    const int mtiles = N / BM;            // 64
    const int vtiles = (V + BN - 1) / BN; // 393
    const long Vpad = (long)vtiles * BN;  // 50304

    char* ws = (char*)d_ws;
    size_t off = 0;
    auto alloc = [&](size_t bytes) {
        void* p = ws + off;
        off += (bytes + 255) & ~(size_t)255;
        return p;
    };
    unsigned char* e_f8 = (unsigned char*)alloc((size_t)N * D);
    unsigned char* c_f8 = (unsigned char*)alloc((size_t)Vpad * D);
    // zero-init region: row_sum[N] | gacc[2] (gacc unused but harmless)
    const int zwords = N + 2;
    float* row_sum = (float*)alloc((size_t)zwords * 4);
    float* tgt     = (float*)alloc((size_t)N * 4);

    const long ne  = (long)N * D;         // 8,388,608  = 2048 blocks * 4096
    const long ncs = (long)V * D;         // 51,463,168 (multiple of 16)
    const long ncd = Vpad * D;            // 51,511,296 = 12576 blocks * 4096
    const int eblocks = (int)(ne / (256 * 16));
    const int cblocks = (int)(ncd / (256 * 16));
    cast_all_fp8<<<eblocks + cblocks, 256, 0, stream>>>(
        e, c, e_f8, c_f8, (unsigned int*)row_sum, zwords, ncs, eblocks);

    dim3 grid(mtiles, vtiles);
    gemm_lse_partial<<<grid, 256, 0, stream>>>(e_f8, c_f8, bias, targets,
                                               row_sum, tgt, N, D, V);

    finish<<<1, 1024, 0, stream>>>(row_sum, tgt, targets, out, N);
}